// Round 11
// baseline (1210.315 us; speedup 1.0000x reference)
//
#include <hip/hip_runtime.h>
#include <hip/hip_bf16.h>
#include <math.h>

// Problem shape (fixed): B=8, L=2048, D=1024, n=16, d=64
#define BATCH 8
#define SEQL  2048
#define DIM   1024
#define MROWS (BATCH * SEQL)   // 16384

typedef _Float16 f16;
typedef _Float16 f16x8 __attribute__((ext_vector_type(8)));
typedef _Float16 f16x4 __attribute__((ext_vector_type(4)));
typedef _Float16 f16x2 __attribute__((ext_vector_type(2)));
typedef float f32x4 __attribute__((ext_vector_type(4)));

typedef const __attribute__((address_space(1))) void* gp_t;
typedef __attribute__((address_space(3))) void* lp_t;
#define GLL(src, dst) __builtin_amdgcn_global_load_lds((gp_t)(src), (lp_t)(dst), 16, 0, 0)

// ---------------------------------------------------------------------------
__global__ __launch_bounds__(128) void zero_flags(int* f) { f[threadIdx.x] = 0; }

// fp32 -> f16 convert, 8 elems/thread
__global__ __launch_bounds__(256) void cvt_f32_f16(const float* __restrict__ in,
                                                   f16* __restrict__ out, int n8)
{
    const int i = blockIdx.x * 256 + threadIdx.x;
    if (i >= n8) return;
    const float4* p = (const float4*)in + (size_t)i * 2;
    const float4 a = p[0], b = p[1];
    f16x8 v;
    v[0] = (f16)a.x; v[1] = (f16)a.y; v[2] = (f16)a.z; v[3] = (f16)a.w;
    v[4] = (f16)b.x; v[5] = (f16)b.y; v[6] = (f16)b.z; v[7] = (f16)b.w;
    *(f16x8*)(out + (size_t)i * 8) = v;
}

// ---------------------------------------------------------------------------
// 256x256-tile 8-phase f16 MFMA GEMM tile (R8-proven body), as an inlined
// device function with runtime bm/bn and a passed LDS base (128 KiB).
// MODE 0: fp32 C0, N=1024.  MODE 1: N=2048 split: col<1024 -> f16 k (C0),
// col>=1024 -> sigmoid(+bias) f16 g (C1).
template<int MODE>
__device__ __forceinline__ void gemm_tile(const f16* __restrict__ A,
                                          const f16* __restrict__ Bw,
                                          const float* __restrict__ bias,
                                          void* __restrict__ C0,
                                          void* __restrict__ C1,
                                          int bm, int bn, f16* lds)
{
    constexpr int K   = 1024;
    constexpr int NKT = 16;             // K/64

    const int tid = threadIdx.x;
    const int w = tid >> 6, l = tid & 63;
    const int wm = w >> 2, wn = w & 3;
    const int lrow = l & 15;
    const int l7 = l & 7, lk = l >> 4;

    // staging geometry: 512 threads x 2 x 16B = one 128x64 half-tile
    const int srl   = tid >> 3;
    const int sg    = tid & 7;
    const int scolx = (sg ^ (srl & 7)) * 8;     // inverse-swizzled source col

    // swizzled ds-read granule offsets (elems) for ks=0/1
    const int g0 = ((lk) ^ l7) * 8;
    const int g1 = ((4 + lk) ^ l7) * 8;

#define STAGE(t, m, P, rowbase, h)                                                       \
    do {                                                                                 \
        const int _rf0 = (h) * 128 + srl;                                                \
        GLL((P) + (size_t)((rowbase) + _rf0) * K + (t) * 64 + scolx,                     \
            lds + (((t) & 1) * 2 + (m)) * 16384 + _rf0 * 64 + sg * 8);                   \
        const int _rf1 = _rf0 + 64;                                                      \
        GLL((P) + (size_t)((rowbase) + _rf1) * K + (t) * 64 + scolx,                     \
            lds + (((t) & 1) * 2 + (m)) * 16384 + _rf1 * 64 + sg * 8);                   \
    } while (0)

    f32x4 acc[8][4];
    #pragma unroll
    for (int mi = 0; mi < 8; ++mi)
        #pragma unroll
        for (int ni = 0; ni < 4; ++ni) acc[mi][ni] = (f32x4){0.f, 0.f, 0.f, 0.f};

    f16x8 bf[4][2];

#define PHASE(p, cur, STG, LOAD_B)                                                       \
    do {                                                                                 \
        const f16* _ab = lds + (cur) * 32768;                                            \
        const int _ar = (wm * 128 + (2 * (p)) * 16 + lrow) * 64;                         \
        f16x8 a00 = *(const f16x8*)(_ab + _ar + g0);                                     \
        f16x8 a01 = *(const f16x8*)(_ab + _ar + g1);                                     \
        f16x8 a10 = *(const f16x8*)(_ab + _ar + 1024 + g0);                              \
        f16x8 a11 = *(const f16x8*)(_ab + _ar + 1024 + g1);                              \
        if (LOAD_B) {                                                                    \
            const f16* _bb = _ab + 16384;                                                \
            _Pragma("unroll")                                                            \
            for (int ni = 0; ni < 4; ++ni) {                                             \
                const int _br = (wn * 64 + ni * 16 + lrow) * 64;                         \
                bf[ni][0] = *(const f16x8*)(_bb + _br + g0);                             \
                bf[ni][1] = *(const f16x8*)(_bb + _br + g1);                             \
            }                                                                            \
        }                                                                                \
        STG;                                                                             \
        __builtin_amdgcn_s_barrier();                                                    \
        asm volatile("s_waitcnt lgkmcnt(0)" ::: "memory");                               \
        __builtin_amdgcn_sched_barrier(0);                                               \
        __builtin_amdgcn_s_setprio(1);                                                   \
        _Pragma("unroll")                                                                \
        for (int ni = 0; ni < 4; ++ni) {                                                 \
            acc[2*(p)][ni]   = __builtin_amdgcn_mfma_f32_16x16x32_f16(a00, bf[ni][0], acc[2*(p)][ni], 0, 0, 0);   \
            acc[2*(p)][ni]   = __builtin_amdgcn_mfma_f32_16x16x32_f16(a01, bf[ni][1], acc[2*(p)][ni], 0, 0, 0);   \
            acc[2*(p)+1][ni] = __builtin_amdgcn_mfma_f32_16x16x32_f16(a10, bf[ni][0], acc[2*(p)+1][ni], 0, 0, 0); \
            acc[2*(p)+1][ni] = __builtin_amdgcn_mfma_f32_16x16x32_f16(a11, bf[ni][1], acc[2*(p)+1][ni], 0, 0, 0); \
        }                                                                                \
        __builtin_amdgcn_s_setprio(0);                                                   \
    } while (0)

    // prologue: A(0),B(0),B(1); wait A(0)+B(0) (first 8 of 12 loads)
    STAGE(0, 0, A, bm, 0);  STAGE(0, 0, A, bm, 1);
    STAGE(0, 1, Bw, bn, 0); STAGE(0, 1, Bw, bn, 1);
    STAGE(1, 1, Bw, bn, 0); STAGE(1, 1, Bw, bn, 1);
    asm volatile("s_waitcnt vmcnt(4)" ::: "memory");
    __builtin_amdgcn_s_barrier();

    for (int t = 0; t < NKT; ++t) {
        const int cur = t & 1;
        PHASE(0, cur, { if (t + 1 < NKT) STAGE(t + 1, 0, A, bm, 0); }, 1);
        __builtin_amdgcn_s_barrier();
        PHASE(1, cur, { if (t + 1 < NKT) STAGE(t + 1, 0, A, bm, 1); }, 0);
        __builtin_amdgcn_s_barrier();
        PHASE(2, cur, { if (t + 2 < NKT) STAGE(t + 2, 1, Bw, bn, 0); }, 0);
        __builtin_amdgcn_s_barrier();
        PHASE(3, cur, { if (t + 2 < NKT) STAGE(t + 2, 1, Bw, bn, 1); }, 0);
        if (t + 2 < NKT)      asm volatile("s_waitcnt vmcnt(4)" ::: "memory");
        else if (t + 1 < NKT) asm volatile("s_waitcnt vmcnt(0)" ::: "memory");
        __builtin_amdgcn_s_barrier();
    }
#undef PHASE
#undef STAGE

    // epilogue: C/D layout col = l&15, row = (l>>4)*4 + r
    const int orow = (l >> 4) * 4;
    const int ocol = l & 15;
    #pragma unroll
    for (int mi = 0; mi < 8; ++mi) {
        #pragma unroll
        for (int ni = 0; ni < 4; ++ni) {
            const int col  = bn + wn * 64 + ni * 16 + ocol;
            const int row0 = bm + wm * 128 + mi * 16 + orow;
            #pragma unroll
            for (int r = 0; r < 4; ++r) {
                float v = acc[mi][ni][r];
                if (MODE == 0) {
                    ((float*)C0)[(size_t)(row0 + r) * DIM + col] = v;
                } else {
                    if (col < DIM) {
                        ((f16*)C0)[(size_t)(row0 + r) * DIM + col] = (f16)v;     // k
                    } else {
                        v += bias[col - DIM];
                        v = 1.f / (1.f + __expf(-v));                            // g
                        ((f16*)C1)[(size_t)(row0 + r) * DIM + (col - DIM)] = (f16)v;
                    }
                }
            }
        }
    }
}

// ---------------------------------------------------------------------------
// DPP cross-lane add (VALU latency). CTRL compile-time.
template<int CTRL>
__device__ __forceinline__ float dpp_add_f(float s) {
    int t = __builtin_amdgcn_update_dpp(0, __float_as_int(s), CTRL, 0xF, 0xF, true);
    return s + __int_as_float(t);
}

__device__ __forceinline__ float sumsq4(f16x2 a, f16x2 b) {
    return __builtin_amdgcn_fdot2(a, a, __builtin_amdgcn_fdot2(b, b, 0.f, false), false);
}

#define PF 16   // scan prefetch depth (divides 256)

// ---------------------------------------------------------------------------
// Persistent pipelined kernel: 256 blocks (1/CU, 128KB LDS).
//  blocks 0..223  : GEMM workers. XCD/batch x = bid&7, lane j = bid>>3 (0..27).
//                   kg tiles (chunk-major within batch), then out tiles gated
//                   on scan progress.
//  blocks 224..255: scan, 1 wave. batch b = (bid-224)&7, head-quad q = >>3.
// Flags: kgf[b][c] counts kg tiles (to 8); ofl[b][c] counts scan waves (to 4).
// Batch pinned to XCD (blockIdx%8 round-robin) -> producer/consumer share L2.
__global__ __launch_bounds__(512, 2) void mega(const f16* __restrict__ xh,
                                               const f16* __restrict__ Wcat,
                                               const float* __restrict__ bkg,
                                               f16* __restrict__ Kh,
                                               f16* __restrict__ Gh,
                                               f16* __restrict__ Ov,     // = xh
                                               const f16* __restrict__ Wouth,
                                               float* __restrict__ out,
                                               int* __restrict__ flags)
{
    __shared__ f16 lds[2 * 2 * 16384];   // 128 KiB
    int* kgf = flags;                    // [8][8] -> 8
    int* ofl = flags + 64;               // [8][8] -> 4

    const int bid = blockIdx.x;
    if (bid < 224) {
        // ---------------- GEMM worker ----------------
        const int x = bid & 7;          // XCD == batch
        const int j = bid >> 3;         // 0..27
        const int tid = threadIdx.x;

        // kg phase: 64 tiles per batch (8 chunks x 8 n), chunk-major
        for (int r = 0; r < 3; ++r) {
            const int s = j + 28 * r;
            if (s >= 64) break;
            const int c = s >> 3, n = s & 7;
            gemm_tile<1>(xh, Wcat, bkg, Kh, Gh, x * 2048 + c * 256, n * 256, lds);
            __syncthreads();            // drain all waves' stores (barrier implies vmcnt 0)
            if (tid == 0) {
                __threadfence();
                __hip_atomic_fetch_add(&kgf[x * 8 + c], 1,
                                       __ATOMIC_RELEASE, __HIP_MEMORY_SCOPE_AGENT);
            }
        }

        // out phase: 32 tiles per batch (8 chunks x 4 n), chunk-major
        for (int r = 0; r < 2; ++r) {
            const int s = j + 28 * r;
            if (s >= 32) break;
            const int c = s >> 2, n = s & 3;
            if (tid == 0) {
                while (__hip_atomic_load(&ofl[x * 8 + c],
                                         __ATOMIC_ACQUIRE, __HIP_MEMORY_SCOPE_AGENT) < 4)
                    __builtin_amdgcn_s_sleep(32);
            }
            __syncthreads();
            gemm_tile<0>(Ov, Wouth, nullptr, out, nullptr,
                         x * 2048 + c * 256, n * 256, lds);
            __syncthreads();
        }
    } else {
        // ---------------- scan (1 wave) ----------------
        if (threadIdx.x >= 64) return;
        const int sid = bid - 224;
        const int b = sid & 7, q = sid >> 3;   // batch, head-quad
        const int l = threadIdx.x;

        const size_t base = (size_t)b * (SEQL * DIM) + (size_t)(q * 256 + l * 4);
        f16x2 h01 = (f16x2){(f16)0.f, (f16)0.f};
        f16x2 h23 = (f16x2){(f16)0.f, (f16)0.f};

        #define SCAN_STEP(kc, gc)                                                      \
            do {                                                                       \
                const f16x2 k01 = __builtin_shufflevector((kc), (kc), 0, 1);           \
                const f16x2 k23 = __builtin_shufflevector((kc), (kc), 2, 3);           \
                const f16x2 g01 = __builtin_shufflevector((gc), (gc), 0, 1);           \
                const f16x2 g23 = __builtin_shufflevector((gc), (gc), 2, 3);           \
                const f16x2 u01 = h01 * g01;                                           \
                const f16x2 u23 = h23 * g23;                                           \
                float s = sumsq4(h01, h23);                                            \
                s = dpp_add_f<0xB1>(s);                                                \
                s = dpp_add_f<0x4E>(s);                                                \
                s = dpp_add_f<0x141>(s);                                               \
                s = dpp_add_f<0x140>(s);                                               \
                const float inv = __builtin_amdgcn_rsqf(fmaf(s, 0.015625f, 1e-8f));    \
                const f16 ih = (f16)inv;                                               \
                const f16x2 iv = (f16x2){ih, ih};                                      \
                h01 = u01 * iv + k01;                                                  \
                h23 = u23 * iv + k23;                                                  \
                f16x4 o;                                                               \
                o[0] = h01[0]; o[1] = h01[1]; o[2] = h23[0]; o[3] = h23[1];            \
                *(f16x4*)(Ov + off) = o;                                               \
                off += DIM;                                                            \
            } while (0)

        for (int c = 0; c < 8; ++c) {
            // wait for this chunk's 8 kg tiles
            while (__hip_atomic_load(&kgf[b * 8 + c],
                                     __ATOMIC_ACQUIRE, __HIP_MEMORY_SCOPE_AGENT) < 8)
                __builtin_amdgcn_s_sleep(16);

            size_t off = base + (size_t)(c * 256) * DIM;
            f16x4 kb[PF], gb[PF];
            #pragma unroll
            for (int u = 0; u < PF; ++u) {
                kb[u] = *(const f16x4*)(Kh + off + (size_t)u * DIM);
                gb[u] = *(const f16x4*)(Gh + off + (size_t)u * DIM);
            }
            for (int t0 = 0; t0 + PF < 256; t0 += PF) {
                #pragma unroll
                for (int u = 0; u < PF; ++u) {
                    const f16x4 kc = kb[u], gc = gb[u];
                    const size_t poff = off + (size_t)PF * DIM;   // stays in chunk
                    kb[u] = *(const f16x4*)(Kh + poff);
                    gb[u] = *(const f16x4*)(Gh + poff);
                    SCAN_STEP(kc, gc);
                }
            }
            #pragma unroll
            for (int u = 0; u < PF; ++u) {
                const f16x4 kc = kb[u], gc = gb[u];
                SCAN_STEP(kc, gc);
            }
            __threadfence();
            if (l == 0)
                __hip_atomic_fetch_add(&ofl[b * 8 + c], 1,
                                       __ATOMIC_RELEASE, __HIP_MEMORY_SCOPE_AGENT);
        }
        #undef SCAN_STEP
    }
}

// ---------------------------------------------------------------------------
extern "C" void kernel_launch(void* const* d_in, const int* in_sizes, int n_in,
                              void* d_out, int out_size, void* d_ws, size_t ws_size,
                              hipStream_t stream) {
    const float* x    = (const float*)d_in[0];
    const float* Wk   = (const float*)d_in[1];
    const float* Wkg  = (const float*)d_in[2];
    const float* bkg  = (const float*)d_in[3];
    const float* Wout = (const float*)d_in[4];
    float* out = (float*)d_out;

    // workspace (f16): xh/Kh/Gh 32MB each + Wcat 4MB + Wouth 2MB + flags
    f16* xh    = (f16*)d_ws;                         // [M, D]; scan output reuses it
    f16* Kh    = xh    + (size_t)MROWS * DIM;
    f16* Gh    = Kh    + (size_t)MROWS * DIM;
    f16* Wcat  = Gh    + (size_t)MROWS * DIM;        // [2048, 1024]: Wk ; Wkg
    f16* Wouth = Wcat  + (size_t)2 * DIM * DIM;
    int* flags = (int*)(Wouth + (size_t)DIM * DIM);  // 128 ints

    zero_flags<<<dim3(1), dim3(128), 0, stream>>>(flags);

    const int nx8 = MROWS * DIM / 8;
    const int nw8 = DIM * DIM / 8;
    cvt_f32_f16<<<dim3(nx8 / 256), dim3(256), 0, stream>>>(x, xh, nx8);
    cvt_f32_f16<<<dim3(nw8 / 256), dim3(256), 0, stream>>>(Wk, Wcat, nw8);
    cvt_f32_f16<<<dim3(nw8 / 256), dim3(256), 0, stream>>>(Wkg, Wcat + (size_t)DIM * DIM, nw8);
    cvt_f32_f16<<<dim3(nw8 / 256), dim3(256), 0, stream>>>(Wout, Wouth, nw8);

    // fused pipeline: kg-GEMM -> scan -> out-GEMM, flag-gated, batch-per-XCD
    mega<<<dim3(256), dim3(512), 0, stream>>>(xh, Wcat, bkg, Kh, Gh,
                                              xh /* o overwrites xh */, Wouth,
                                              out, flags);
}

// Round 12
// 327.749 us; speedup vs baseline: 3.6928x; 3.6928x over previous
//
#include <hip/hip_runtime.h>
#include <hip/hip_bf16.h>
#include <math.h>

// Problem shape (fixed): B=8, L=2048, D=1024, n=16, d=64
#define BATCH 8
#define SEQL  2048
#define DIM   1024
#define NHEAD 16
#define MROWS (BATCH * SEQL)   // 16384

typedef _Float16 f16;
typedef _Float16 f16x8 __attribute__((ext_vector_type(8)));
typedef _Float16 f16x4 __attribute__((ext_vector_type(4)));
typedef _Float16 f16x2 __attribute__((ext_vector_type(2)));
typedef float f32x4 __attribute__((ext_vector_type(4)));

typedef const __attribute__((address_space(1))) void* gp_t;
typedef __attribute__((address_space(3))) void* lp_t;
#define GLL(src, dst) __builtin_amdgcn_global_load_lds((gp_t)(src), (lp_t)(dst), 16, 0, 0)

// ---------------------------------------------------------------------------
// fp32 -> f16 convert, 8 elems/thread
__global__ __launch_bounds__(256) void cvt_f32_f16(const float* __restrict__ in,
                                                   f16* __restrict__ out, int n8)
{
    const int i = blockIdx.x * 256 + threadIdx.x;
    if (i >= n8) return;
    const float4* p = (const float4*)in + (size_t)i * 2;
    const float4 a = p[0], b = p[1];
    f16x8 v;
    v[0] = (f16)a.x; v[1] = (f16)a.y; v[2] = (f16)a.z; v[3] = (f16)a.w;
    v[4] = (f16)b.x; v[5] = (f16)b.y; v[6] = (f16)b.z; v[7] = (f16)b.w;
    *(f16x8*)(out + (size_t)i * 8) = v;
}

// ---------------------------------------------------------------------------
// 256x256-tile 8-phase f16 MFMA GEMM (T3+T4 counted vmcnt, T2 swizzle via
// inverse-swizzled global source, T5 setprio). R8-proven (294us config).
// MODE 0: fp32 C0, N=1024.  MODE 1: N=2048 split: col<1024 -> f16 k (C0),
// col>=1024 -> sigmoid(+bias) f16 g (C1).
template<int MODE>
__global__ __launch_bounds__(512, 2) void gemm8(const f16* __restrict__ A,
                                                const f16* __restrict__ Bw,
                                                const float* __restrict__ bias,
                                                void* __restrict__ C0,
                                                void* __restrict__ C1)
{
    constexpr int K   = 1024;
    constexpr int NTI = MODE ? 8 : 4;   // N/256
    constexpr int NKT = 16;             // K/64
    __shared__ f16 lds[2][2][256 * 64]; // [buf][A=0/B=1], 128 KiB

    const int tid = threadIdx.x;
    const int w = tid >> 6, l = tid & 63;
    const int wm = w >> 2, wn = w & 3;
    const int lrow = l & 15;
    const int l7 = l & 7, lk = l >> 4;

    // bijective XCD swizzle (grid % 8 == 0)
    const int cpx = gridDim.x >> 3;
    const int lt  = (blockIdx.x & 7) * cpx + (blockIdx.x >> 3);
    const int bm  = (lt / NTI) * 256;
    const int bn  = (lt % NTI) * 256;

    // staging geometry: 512 threads x 2 x 16B = one 128x64 half-tile
    const int srl   = tid >> 3;                 // 0..63 row within 64-row round
    const int sg    = tid & 7;                  // LDS granule slot
    const int scolx = (sg ^ (srl & 7)) * 8;     // inverse-swizzled source col

    // swizzled ds-read granule offsets (elems) for ks=0/1
    const int g0 = ((lk) ^ l7) * 8;
    const int g1 = ((4 + lk) ^ l7) * 8;

#define STAGE(t, m, P, rowbase, h)                                                       \
    do {                                                                                 \
        const int _rf0 = (h) * 128 + srl;                                                \
        GLL((P) + (size_t)((rowbase) + _rf0) * K + (t) * 64 + scolx,                     \
            &lds[(t) & 1][m][_rf0 * 64 + sg * 8]);                                       \
        const int _rf1 = _rf0 + 64;                                                      \
        GLL((P) + (size_t)((rowbase) + _rf1) * K + (t) * 64 + scolx,                     \
            &lds[(t) & 1][m][_rf1 * 64 + sg * 8]);                                       \
    } while (0)

    f32x4 acc[8][4];
    #pragma unroll
    for (int mi = 0; mi < 8; ++mi)
        #pragma unroll
        for (int ni = 0; ni < 4; ++ni) acc[mi][ni] = (f32x4){0.f, 0.f, 0.f, 0.f};

    f16x8 bf[4][2];

#define PHASE(p, cur, STG, LOAD_B)                                                       \
    do {                                                                                 \
        const f16* _ab = &lds[cur][0][0];                                                \
        const int _ar = (wm * 128 + (2 * (p)) * 16 + lrow) * 64;                         \
        f16x8 a00 = *(const f16x8*)(_ab + _ar + g0);                                     \
        f16x8 a01 = *(const f16x8*)(_ab + _ar + g1);                                     \
        f16x8 a10 = *(const f16x8*)(_ab + _ar + 1024 + g0);                              \
        f16x8 a11 = *(const f16x8*)(_ab + _ar + 1024 + g1);                              \
        if (LOAD_B) {                                                                    \
            const f16* _bb = &lds[cur][1][0];                                            \
            _Pragma("unroll")                                                            \
            for (int ni = 0; ni < 4; ++ni) {                                             \
                const int _br = (wn * 64 + ni * 16 + lrow) * 64;                         \
                bf[ni][0] = *(const f16x8*)(_bb + _br + g0);                             \
                bf[ni][1] = *(const f16x8*)(_bb + _br + g1);                             \
            }                                                                            \
        }                                                                                \
        STG;                                                                             \
        __builtin_amdgcn_s_barrier();                                                    \
        asm volatile("s_waitcnt lgkmcnt(0)" ::: "memory");                               \
        __builtin_amdgcn_sched_barrier(0);                                               \
        __builtin_amdgcn_s_setprio(1);                                                   \
        _Pragma("unroll")                                                                \
        for (int ni = 0; ni < 4; ++ni) {                                                 \
            acc[2*(p)][ni]   = __builtin_amdgcn_mfma_f32_16x16x32_f16(a00, bf[ni][0], acc[2*(p)][ni], 0, 0, 0);   \
            acc[2*(p)][ni]   = __builtin_amdgcn_mfma_f32_16x16x32_f16(a01, bf[ni][1], acc[2*(p)][ni], 0, 0, 0);   \
            acc[2*(p)+1][ni] = __builtin_amdgcn_mfma_f32_16x16x32_f16(a10, bf[ni][0], acc[2*(p)+1][ni], 0, 0, 0); \
            acc[2*(p)+1][ni] = __builtin_amdgcn_mfma_f32_16x16x32_f16(a11, bf[ni][1], acc[2*(p)+1][ni], 0, 0, 0); \
        }                                                                                \
        __builtin_amdgcn_s_setprio(0);                                                   \
    } while (0)

    // prologue: A(0),B(0),B(1); wait A(0)+B(0) (first 8 of 12 loads)
    STAGE(0, 0, A, bm, 0);  STAGE(0, 0, A, bm, 1);
    STAGE(0, 1, Bw, bn, 0); STAGE(0, 1, Bw, bn, 1);
    STAGE(1, 1, Bw, bn, 0); STAGE(1, 1, Bw, bn, 1);
    asm volatile("s_waitcnt vmcnt(4)" ::: "memory");
    __builtin_amdgcn_s_barrier();

    for (int t = 0; t < NKT; ++t) {
        const int cur = t & 1;
        PHASE(0, cur, { if (t + 1 < NKT) STAGE(t + 1, 0, A, bm, 0); }, 1);
        __builtin_amdgcn_s_barrier();
        PHASE(1, cur, { if (t + 1 < NKT) STAGE(t + 1, 0, A, bm, 1); }, 0);
        __builtin_amdgcn_s_barrier();
        PHASE(2, cur, { if (t + 2 < NKT) STAGE(t + 2, 1, Bw, bn, 0); }, 0);
        __builtin_amdgcn_s_barrier();
        PHASE(3, cur, { if (t + 2 < NKT) STAGE(t + 2, 1, Bw, bn, 1); }, 0);
        if (t + 2 < NKT)      asm volatile("s_waitcnt vmcnt(4)" ::: "memory");
        else if (t + 1 < NKT) asm volatile("s_waitcnt vmcnt(0)" ::: "memory");
        __builtin_amdgcn_s_barrier();
    }
#undef PHASE
#undef STAGE

    // epilogue: C/D layout col = l&15, row = (l>>4)*4 + r
    const int orow = (l >> 4) * 4;
    const int ocol = l & 15;
    #pragma unroll
    for (int mi = 0; mi < 8; ++mi) {
        #pragma unroll
        for (int ni = 0; ni < 4; ++ni) {
            const int col  = bn + wn * 64 + ni * 16 + ocol;
            const int row0 = bm + wm * 128 + mi * 16 + orow;
            #pragma unroll
            for (int r = 0; r < 4; ++r) {
                float v = acc[mi][ni][r];
                if (MODE == 0) {
                    ((float*)C0)[(size_t)(row0 + r) * DIM + col] = v;
                } else {
                    if (col < DIM) {
                        ((f16*)C0)[(size_t)(row0 + r) * DIM + col] = (f16)v;     // k
                    } else {
                        v += bias[col - DIM];
                        v = 1.f / (1.f + __expf(-v));                            // g
                        ((f16*)C1)[(size_t)(row0 + r) * DIM + (col - DIM)] = (f16)v;
                    }
                }
            }
        }
    }
}

// ---------------------------------------------------------------------------
// DPP cross-lane add (VALU latency). CTRL compile-time.
template<int CTRL>
__device__ __forceinline__ float dpp_add_f(float s) {
    int t = __builtin_amdgcn_update_dpp(0, __float_as_int(s), CTRL, 0xF, 0xF, true);
    return s + __int_as_float(t);
}

#define PF 16   // prefetch depth (steps); divides SEQL

// Scan, 8-lane-per-sequence layout: 16 waves; wave w covers batch w>>1,
// heads (w&1)*8 .. +7. Sequence s = lanes 8s..8s+7; lane owns 8 contiguous
// dims (f16x8, one dwordx4 load per operand per step; wave load = 1KB
// coalesced). Reduce = 3 DPP hops (xor1, xor2 quad_perm; row_half_mirror
// (^7) acts as xor4 once quads are uniform — all within the 8-lane group).
// Chain: 2-deep fdot2 tree -> 3 DPP -> fma -> rsq -> cvt -> pk_fma (~80cy
// vs 4-hop/16-lane's ~130). Math identical to the proven R8 config:
// inv = rsq(S/64 + 1e-8); h' = (h*g)*inv + k.
__global__ __launch_bounds__(64) void scan_kernel(const f16* __restrict__ Kv,
                                                  const f16* __restrict__ Gv,
                                                  f16* __restrict__ Ov)
{
    const int w = blockIdx.x;     // 0..15
    const int l = threadIdx.x;

    const size_t base = (size_t)(w >> 1) * (SEQL * DIM) + (size_t)((w & 1) * 512 + l * 8);
    f16x2 h0 = (f16x2){(f16)0.f, (f16)0.f};
    f16x2 h1 = h0, h2 = h0, h3 = h0;

    f16x8 kb[PF], gb[PF];
    #pragma unroll
    for (int u = 0; u < PF; ++u) {
        kb[u] = *(const f16x8*)(Kv + base + (size_t)u * DIM);
        gb[u] = *(const f16x8*)(Gv + base + (size_t)u * DIM);
    }

    size_t off = base;

    #define SCAN_STEP(kc, gc)                                                          \
        do {                                                                           \
            const f16x2 k0 = __builtin_shufflevector((kc), (kc), 0, 1);                \
            const f16x2 k1 = __builtin_shufflevector((kc), (kc), 2, 3);                \
            const f16x2 k2 = __builtin_shufflevector((kc), (kc), 4, 5);                \
            const f16x2 k3 = __builtin_shufflevector((kc), (kc), 6, 7);                \
            const f16x2 g0 = __builtin_shufflevector((gc), (gc), 0, 1);                \
            const f16x2 g1 = __builtin_shufflevector((gc), (gc), 2, 3);                \
            const f16x2 g2 = __builtin_shufflevector((gc), (gc), 4, 5);                \
            const f16x2 g3 = __builtin_shufflevector((gc), (gc), 6, 7);                \
            const f16x2 u0 = h0 * g0, u1 = h1 * g1;   /* v_pk_mul_f16 */               \
            const f16x2 u2 = h2 * g2, u3 = h3 * g3;                                    \
            /* 2-deep fdot2 tree for Sum(h^2) over this lane's 8 dims */               \
            const float sA = __builtin_amdgcn_fdot2(h1, h1,                            \
                               __builtin_amdgcn_fdot2(h0, h0, 0.f, false), false);     \
            const float sB = __builtin_amdgcn_fdot2(h3, h3,                            \
                               __builtin_amdgcn_fdot2(h2, h2, 0.f, false), false);     \
            float s = sA + sB;                                                         \
            s = dpp_add_f<0xB1>(s);   /* xor1: quad_perm [1,0,3,2] */                  \
            s = dpp_add_f<0x4E>(s);   /* xor2: quad_perm [2,3,0,1] */                  \
            s = dpp_add_f<0x141>(s);  /* ^7 row_half_mirror == xor4 post-uniform */    \
            const float inv = __builtin_amdgcn_rsqf(fmaf(s, 0.015625f, 1e-8f));        \
            const f16 ih = (f16)inv;                                                   \
            const f16x2 iv = (f16x2){ih, ih};                                          \
            h0 = u0 * iv + k0; h1 = u1 * iv + k1;     /* v_pk_fma_f16 */               \
            h2 = u2 * iv + k2; h3 = u3 * iv + k3;                                      \
            f16x8 o;                                                                   \
            o[0] = h0[0]; o[1] = h0[1]; o[2] = h1[0]; o[3] = h1[1];                    \
            o[4] = h2[0]; o[5] = h2[1]; o[6] = h3[0]; o[7] = h3[1];                    \
            *(f16x8*)(Ov + off) = o;                                                   \
            off += DIM;                                                                \
        } while (0)

    for (int t0 = 0; t0 + PF < SEQL; t0 += PF) {
        #pragma unroll
        for (int u = 0; u < PF; ++u) {
            const f16x8 kc = kb[u], gc = gb[u];
            const size_t poff = off + (size_t)PF * DIM;   // refill PF ahead
            kb[u] = *(const f16x8*)(Kv + poff);
            gb[u] = *(const f16x8*)(Gv + poff);
            SCAN_STEP(kc, gc);
        }
    }
    #pragma unroll
    for (int u = 0; u < PF; ++u) {
        const f16x8 kc = kb[u], gc = gb[u];
        SCAN_STEP(kc, gc);
    }
    #undef SCAN_STEP
}

// ---------------------------------------------------------------------------
extern "C" void kernel_launch(void* const* d_in, const int* in_sizes, int n_in,
                              void* d_out, int out_size, void* d_ws, size_t ws_size,
                              hipStream_t stream) {
    const float* x    = (const float*)d_in[0];
    const float* Wk   = (const float*)d_in[1];
    const float* Wkg  = (const float*)d_in[2];
    const float* bkg  = (const float*)d_in[3];
    const float* Wout = (const float*)d_in[4];
    float* out = (float*)d_out;

    // workspace (f16): xh/Kh/Gh 32MB each + Wcat 4MB + Wout 2MB = 102MB
    f16* xh    = (f16*)d_ws;                         // [M, D]; scan output reuses it
    f16* Kh    = xh    + (size_t)MROWS * DIM;
    f16* Gh    = Kh    + (size_t)MROWS * DIM;
    f16* Wcat  = Gh    + (size_t)MROWS * DIM;        // [2048, 1024]: Wk ; Wkg
    f16* Wouth = Wcat  + (size_t)2 * DIM * DIM;

    const int nx8 = MROWS * DIM / 8;
    const int nw8 = DIM * DIM / 8;
    cvt_f32_f16<<<dim3(nx8 / 256), dim3(256), 0, stream>>>(x, xh, nx8);
    cvt_f32_f16<<<dim3(nw8 / 256), dim3(256), 0, stream>>>(Wk, Wcat, nw8);
    cvt_f32_f16<<<dim3(nw8 / 256), dim3(256), 0, stream>>>(Wkg, Wcat + (size_t)DIM * DIM, nw8);
    cvt_f32_f16<<<dim3(nw8 / 256), dim3(256), 0, stream>>>(Wout, Wouth, nw8);

    // fused k|g GEMM: M=16384, N=2048 -> 64 x 8 = 512 blocks
    gemm8<1><<<dim3(512), dim3(512), 0, stream>>>(xh, Wcat, bkg, Kh, Gh);
    // scan: o -> xh (16 waves, 8 seqs each, 8-lane/3-hop reduce)
    scan_kernel<<<dim3(16), dim3(64), 0, stream>>>(Kh, Gh, xh);
    // out = o @ Wout.T: 64 x 4 = 256 blocks
    gemm8<0><<<dim3(256), dim3(512), 0, stream>>>(xh, Wouth, nullptr, out, nullptr);
}